// Round 7
// baseline (326.652 us; speedup 1.0000x reference)
//
#include <hip/hip_runtime.h>

// Partial-CRF NLL, producer/consumer scan, MX-fp8 K=128 MFMA consumer.
// 64 blocks x 192 threads = {wave0: consumer, wave1+2: producers}.
// Block owns 16 chains = 8 batches x {all-paths, gold}.
//
// P layout: per-hi 28-tag windows: B byte (hi, j) = P[28*hi + j] (j<28),
// 0 for j in [28,32). Tile Tt (7 tiles): D reg (Tt,hi,r) = new P at tag
// 28*hi + 4*Tt + r = lane's own B byte j=4*Tt+r -> D==B, no data movement.
// One mfma_scale_f32_16x16x128_f8f6f4 per tile (scales = 0x7F7F7F7F = 1.0).
// Per-step rescale by POWER-OF-2 part of s1 (exponent bits only, exact);
// eSum (int) accumulates exponents; score = eSum*ln2 + log(final sum).
// fminf(440) pre-clamp before fp8 pack (e4m3fn max 448).
// Producers: unchanged bf16 mult slabs (exp(emit), gold x um), 16-slab ring,
// rows = chains, columns = 32-short hi-windows (28 used + 4 pad).

typedef short s16x4 __attribute__((ext_vector_type(4)));
typedef short s16x8 __attribute__((ext_vector_type(8)));
typedef float f32x4 __attribute__((ext_vector_type(4)));
typedef int   i32x8 __attribute__((ext_vector_type(8)));

constexpr int T = 512, L = 102;
constexpr int MS = 136;        // slab row stride (shorts); 272B rows, 16B-aligned
constexpr int NS = 16;         // ring slabs
constexpr int SLAB = 16 * MS;  // shorts per slab

__device__ __forceinline__ float bf2f(short s) {
  return __uint_as_float(((unsigned)(unsigned short)s) << 16);
}
__device__ __forceinline__ float fp8tof(unsigned b) {  // e4m3fn, sign=0
  const int e = (b >> 3) & 15, m = b & 7;
  return e ? ldexpf((float)(8 + m), e - 10) : ldexpf((float)m, -9);
}

#define SC1 0x7F7F7F7F

// one tile epilogue: w = D * mult * cs, clamp, pack fp8, masked update
#define ETILE(Tt, M0, M1, M2, M3)                                            \
  {                                                                          \
    float w0 = dd[Tt][0] * bf2f(M0) * csf;                                   \
    float w1 = dd[Tt][1] * bf2f(M1) * csf;                                   \
    float w2 = dd[Tt][2] * bf2f(M2) * csf;                                   \
    float w3 = dd[Tt][3] * bf2f(M3) * csf;                                   \
    w0 = fminf(w0, 440.f); w1 = fminf(w1, 440.f);                            \
    w2 = fminf(w2, 440.f); w3 = fminf(w3, 440.f);                            \
    int d_ = __builtin_amdgcn_cvt_pk_fp8_f32(w0, w1, 0, false);              \
    d_ = __builtin_amdgcn_cvt_pk_fp8_f32(w2, w3, d_, true);                  \
    pk[Tt] = mmv ? (unsigned)d_ : pk[Tt];                                    \
  }

#define STEP(SB, MMVv)                                                       \
  {                                                                          \
    const bool mmv = (MMVv) != 0;                                            \
    const short* sl = mlb + (SB) + c * MS + 32 * hi;                         \
    const s16x8 A0 = *(const s16x8*)(sl + 0);                                \
    const s16x8 A1 = *(const s16x8*)(sl + 8);                                \
    const s16x8 A2 = *(const s16x8*)(sl + 16);                               \
    const s16x4 A3 = *(const s16x4*)(sl + 24);                               \
    i32x8 bb;                                                                \
    bb[0] = (int)pk[0]; bb[1] = (int)pk[1]; bb[2] = (int)pk[2];              \
    bb[3] = (int)pk[3]; bb[4] = (int)pk[4]; bb[5] = (int)pk[5];              \
    bb[6] = (int)pk[6]; bb[7] = 0;                                           \
    f32x4 dd[7];                                                             \
    dd[0] = __builtin_amdgcn_mfma_scale_f32_16x16x128_f8f6f4(                \
        ea[0], bb, zf, 0, 0, 0, SC1, 0, SC1);                                \
    dd[1] = __builtin_amdgcn_mfma_scale_f32_16x16x128_f8f6f4(                \
        ea[1], bb, zf, 0, 0, 0, SC1, 0, SC1);                                \
    dd[2] = __builtin_amdgcn_mfma_scale_f32_16x16x128_f8f6f4(                \
        ea[2], bb, zf, 0, 0, 0, SC1, 0, SC1);                                \
    dd[3] = __builtin_amdgcn_mfma_scale_f32_16x16x128_f8f6f4(                \
        ea[3], bb, zf, 0, 0, 0, SC1, 0, SC1);                                \
    dd[4] = __builtin_amdgcn_mfma_scale_f32_16x16x128_f8f6f4(                \
        ea[4], bb, zf, 0, 0, 0, SC1, 0, SC1);                                \
    dd[5] = __builtin_amdgcn_mfma_scale_f32_16x16x128_f8f6f4(                \
        ea[5], bb, zf, 0, 0, 0, SC1, 0, SC1);                                \
    dd[6] = __builtin_amdgcn_mfma_scale_f32_16x16x128_f8f6f4(                \
        ea[6], bb, zf, 0, 0, 0, SC1, 0, SC1);                                \
    const float w1s = dd[0][1] * bf2f(A0[1]);  /* tag-1 value at hi=0 */     \
    const float sA  = __shfl(w1s, c);          /* lane c = (c, hi=0) */      \
    const int   ex  = (int)((__float_as_uint(sA) >> 23) & 255u) - 127;       \
    const float csf = __uint_as_float((unsigned)(127 - ex) << 23);           \
    eSum += mmv ? ex : 0;                                                    \
    ETILE(0, A0[0], A0[1], A0[2], A0[3])                                     \
    ETILE(1, A0[4], A0[5], A0[6], A0[7])                                     \
    ETILE(2, A1[0], A1[1], A1[2], A1[3])                                     \
    ETILE(3, A1[4], A1[5], A1[6], A1[7])                                     \
    ETILE(4, A2[0], A2[1], A2[2], A2[3])                                     \
    ETILE(5, A2[4], A2[5], A2[6], A2[7])                                     \
    ETILE(6, A3[0], A3[1], A3[2], A3[3])                                     \
  }

__global__ __launch_bounds__(192, 1)
void crf_scan(const float* __restrict__ emit,
              const float* __restrict__ trans,
              const unsigned char* __restrict__ mask_b,
              const unsigned char* __restrict__ um_b,
              float* __restrict__ partials)
{
  const int tid = threadIdx.x, wid = tid >> 6, lane = tid & 63;
  const int b8 = blockIdx.x * 8;
  // bool layout: um[0,0,1] always True -> byte1==1 iff uint8, else LE int32
  const int ush = (um_b[1] != 0) ? 0 : 2;

  __shared__ __align__(16) short Ml[NS][16][MS];
  __shared__ unsigned char Kmask[8][T];
  __shared__ int sflags[3];   // [0],[1]: producer progress; [2]: consumer

  volatile int* pf0 = (volatile int*)&sflags[0];
  volatile int* pf1 = (volatile int*)&sflags[1];
  volatile int* cfv = (volatile int*)&sflags[2];

  if (wid != 0) {
    // ===================== producer waves (wid 1,2) =====================
    const int pw   = wid - 1;
    const int boff = pw * 4;                       // my 4 batches
    const int tagp = 2 * lane;                     // tag pair (tagp, tagp+1)
    const int tagc = (tagp <= 100) ? tagp : 100;
    const bool tv  = (tagp <= 100);
    // slab short-offset of this tag pair (28-tag windows padded to 32)
    const int woff = 32 * (tagp / 28) + (tagp - 28 * (tagp / 28));
    const bool wok = (tagp < 112);                 // windows 0..3 only

    for (int i = lane; i < 4 * T; i += 64) {       // my Kmask rows
      const int bb = i >> 9, tt = i & 511;
      Kmask[boff + bb][tt] =
          mask_b[(((size_t)(b8 + boff + bb)) * T + tt) << ush];
    }

    struct SetS { float2 e[4]; int u0[4]; int u1[4]; };
    SetS sA, sB, sC, sD;                           // static names

    auto issue = [&](int t, SetS& S) {
      const int tc = (t < T) ? t : T - 1;
#pragma unroll
      for (int i = 0; i < 4; ++i) {
        const size_t base = ((size_t)(b8 + boff + i) * T + tc) * (size_t)L;
        S.e[i] = *(const float2*)(emit + base + tagc);
        if (ush == 0) {
          const unsigned short us = *(const unsigned short*)(um_b + base + tagc);
          S.u0[i] = us & 255; S.u1[i] = us >> 8;
        } else {
          const uint2 uv = *(const uint2*)(um_b + ((base + tagc) << 2));
          S.u0[i] = (int)uv.x; S.u1[i] = (int)uv.y;
        }
      }
    };
    auto stagewr = [&](int t, SetS& S) {
      short* slab = &Ml[t & (NS - 1)][0][0];
#pragma unroll
      for (int i = 0; i < 4; ++i) {
        const float e0 = tv ? __expf(S.e[i].x) : 0.f;
        const float e1 = tv ? __expf(S.e[i].y) : 0.f;
        const float g0 = S.u0[i] ? e0 : 0.f;
        const float g1 = S.u1[i] ? e1 : 0.f;
        unsigned pe, pg;
        asm("v_cvt_pk_bf16_f32 %0, %1, %2" : "=v"(pe) : "v"(e0), "v"(e1));
        asm("v_cvt_pk_bf16_f32 %0, %1, %2" : "=v"(pg) : "v"(g0), "v"(g1));
        if (wok) {
          *(unsigned*)(slab + (2 * (boff + i))     * MS + woff) = pe;  // all
          *(unsigned*)(slab + (2 * (boff + i) + 1) * MS + woff) = pg;  // gold
        }
      }
    };

    __syncthreads();
    issue(1, sA); issue(2, sB); issue(3, sC); issue(4, sD);
    int csn = 0;
    volatile int* myf = (pw == 0) ? pf0 : pf1;

#define PB(tt, S)                                              \
    {                                                          \
      if ((tt) > NS && csn < (tt) - NS) {                      \
        int v; do { v = *cfv; } while (v < (tt) - NS);         \
        csn = v;                                               \
      }                                                        \
      stagewr((tt), S);                                        \
      asm volatile("s_waitcnt lgkmcnt(0)" ::: "memory");       \
      if (lane == 0) *myf = (tt);                              \
      issue((tt) + 4, S);                                      \
    }
    for (int t0 = 1; t0 <= 505; t0 += 4) {
      PB(t0, sA) PB(t0 + 1, sB) PB(t0 + 2, sC) PB(t0 + 3, sD)
    }
    PB(509, sA) PB(510, sB) PB(511, sC)
#undef PB
  } else {
    // ========================= consumer wave =========================
    if (lane == 0) { sflags[0] = 0; sflags[1] = 0; sflags[2] = 0; }
    const int c = lane & 15, hi = lane >> 4;
    const int myb = c >> 1, batch = b8 + myb, goldc = c & 1;

    // A-frags fp8: tile Tt, lane (c,hi): row c -> out-tag gA; byte j -> k-tag
    // 28*hi + j (j<28), 0 pad otherwise.
    i32x8 ea[7];
#pragma unroll
    for (int Tt = 0; Tt < 7; ++Tt) {
      const int gA = 28 * (c >> 2) + 4 * Tt + (c & 3);
#pragma unroll
      for (int d8 = 0; d8 < 8; ++d8) {
        float v0 = 0.f, v1 = 0.f, v2 = 0.f, v3 = 0.f;
#pragma unroll
        for (int bq = 0; bq < 4; ++bq) {
          const int j = 4 * d8 + bq, ktag = 28 * hi + j;
          float e = 0.f;
          if (j < 28 && ktag < L && gA < L) e = __expf(trans[ktag * L + gA]);
          if (bq == 0) v0 = e; else if (bq == 1) v1 = e;
          else if (bq == 2) v2 = e; else v3 = e;
        }
        int dw = __builtin_amdgcn_cvt_pk_fp8_f32(v0, v1, 0, false);
        dw = __builtin_amdgcn_cvt_pk_fp8_f32(v2, v3, dw, true);
        ea[Tt][d8] = dw;
      }
    }

    // t = 0 init: P0 = exp(e0 + trans[START][tag]) (gold: um-gated),
    // rescaled by 2^-e0 where e0 = exponent(P0[tag1]).
    unsigned pk[7];
    int eSum;
    {
      const size_t e0b = (size_t)batch * T * L;
      const float s10 = __expf(emit[e0b + 1] + trans[100 * L + 1]);
      const int e0 = (int)((__float_as_uint(s10) >> 23) & 255u) - 127;
      const float cs0 = __uint_as_float((unsigned)(127 - e0) << 23);
      eSum = e0;
#pragma unroll
      for (int Tt = 0; Tt < 7; ++Tt) {
        float w[4];
#pragma unroll
        for (int r = 0; r < 4; ++r) {
          const int tg = 28 * hi + 4 * Tt + r;
          float x = 0.f;
          if (tg < L) {
            x = __expf(emit[e0b + tg] + trans[100 * L + tg]);
            if (goldc && !um_b[(e0b + tg) << ush]) x = 0.f;
          }
          w[r] = fminf(x * cs0, 440.f);
        }
        int dw = __builtin_amdgcn_cvt_pk_fp8_f32(w[0], w[1], 0, false);
        dw = __builtin_amdgcn_cvt_pk_fp8_f32(w[2], w[3], dw, true);
        pk[Tt] = (unsigned)dw;
      }
    }

    const short* mlb = &Ml[0][0][0];
    const unsigned* kmr = (const unsigned*)&Kmask[myb][0];
    const f32x4 zf = {0.f, 0.f, 0.f, 0.f};
    int seen = 0;

    __syncthreads();

    for (int t0 = 1; t0 <= 505; t0 += 4) {
      const int t3 = t0 + 3;
      if (seen < t3) {
        int v0, v1;
        do { v0 = *pf0; v1 = *pf1; } while (v0 < t3 || v1 < t3);
        seen = (v0 < v1) ? v0 : v1;
      }
      int sb0 = (t0 & 15) * SLAB;
      int sb1 = ((t0 + 1) & 15) * SLAB;
      int sb2 = ((t0 + 2) & 15) * SLAB;
      int sb3 = ((t0 + 3) & 15) * SLAB;
      asm volatile("" : "+v"(sb0), "+v"(sb1), "+v"(sb2), "+v"(sb3) : "v"(seen));
      const unsigned kl = kmr[(t0 - 1) >> 2];          // bytes t0-1..t0+2
      const unsigned kh = kmr[((t0 - 1) >> 2) + 1];    // byte  t0+3
      const unsigned m0 = (kl >> 8) & 255u, m1 = (kl >> 16) & 255u;
      const unsigned m2 = kl >> 24,         m3 = kh & 255u;
      STEP(sb0, m0)
      STEP(sb1, m1)
      STEP(sb2, m2)
      STEP(sb3, m3)
      asm volatile("s_waitcnt lgkmcnt(0)" ::: "memory");
      if (lane == 0) *cfv = t3;
    }
    {   // tail t = 509..511
      if (seen < 511) {
        int v0, v1;
        do { v0 = *pf0; v1 = *pf1; } while (v0 < 511 || v1 < 511);
        seen = (v0 < v1) ? v0 : v1;
      }
      int sb0 = (509 & 15) * SLAB, sb1 = (510 & 15) * SLAB,
          sb2 = (511 & 15) * SLAB;
      asm volatile("" : "+v"(sb0), "+v"(sb1), "+v"(sb2) : "v"(seen));
      const unsigned kl = kmr[127];                    // bytes 508..511
      const unsigned m0 = (kl >> 8) & 255u, m1 = (kl >> 16) & 255u;
      const unsigned m2 = kl >> 24;
      STEP(sb0, m0)
      STEP(sb1, m1)
      STEP(sb2, m2)
    }

    // final: score = eSum*ln2 + log sum_tag P[tag] * exp(trans[tag][STOP])
    float tot = 0.f;
#pragma unroll
    for (int Tt = 0; Tt < 7; ++Tt) {
#pragma unroll
      for (int r = 0; r < 4; ++r) {
        const int tg = 28 * hi + 4 * Tt + r;
        if (tg < L) {
          const unsigned pb = (pk[Tt] >> (8 * r)) & 255u;
          tot += fp8tof(pb) * __expf(trans[tg * L + 101]);
        }
      }
    }
    tot += __shfl_xor(tot, 16);
    tot += __shfl_xor(tot, 32);
    const float score = (float)eSum * 0.6931471805599453f + __logf(tot);
    float sgn = goldc ? -score : score;
    sgn += __shfl_xor(sgn, 1);
    sgn += __shfl_xor(sgn, 2);
    sgn += __shfl_xor(sgn, 4);
    sgn += __shfl_xor(sgn, 8);
    if (lane == 0) partials[blockIdx.x] = sgn;
  }
}

__global__ void reduce_partials(const float* __restrict__ part,
                                float* __restrict__ out) {
  float v = part[threadIdx.x];
#pragma unroll
  for (int s = 1; s < 64; s <<= 1) v += __shfl_xor(v, s);
  if (threadIdx.x == 0) out[0] = v;
}

extern "C" void kernel_launch(void* const* d_in, const int* in_sizes, int n_in,
                              void* d_out, int out_size, void* d_ws,
                              size_t ws_size, hipStream_t stream) {
  const float* emit = (const float*)d_in[0];
  const float* trn  = (const float*)d_in[1];
  const unsigned char* msk = (const unsigned char*)d_in[2];
  const unsigned char* umk = (const unsigned char*)d_in[3];
  float* out = (float*)d_out;
  float* pw  = (float*)d_ws;   // 64 block partials

  crf_scan<<<dim3(64), dim3(192), 0, stream>>>(emit, trn, msk, umk, pw);
  reduce_partials<<<dim3(1), dim3(64), 0, stream>>>(pw, out);
}